// Round 8
// baseline (1459.962 us; speedup 1.0000x reference)
//
#include <hip/hip_runtime.h>
#include <math.h>

// ---------------- problem constants ----------------
#define NN      1000
#define TLEN    4000
#define BB      16
#define SS      12
#define HH      12
#define HID     64
#define C1N     8
#define C2N     16
#define KW      10
#define L1LEN   3991
#define L2LEN   3982
#define DD      128
#define HE      128

typedef __bf16 bf16x8 __attribute__((ext_vector_type(8)));
typedef float  f32x4  __attribute__((ext_vector_type(4)));
typedef float  f32x2  __attribute__((ext_vector_type(2)));
typedef unsigned long long u64;
typedef __attribute__((address_space(3))) unsigned int       as3_u32;
typedef const __attribute__((address_space(1))) unsigned int as1_u32;

__device__ __forceinline__ void glds16(const void* g, void* l) {
    __builtin_amdgcn_global_load_lds((as1_u32*)g, (as3_u32*)l, 16, 0, 0);
}

__device__ __forceinline__ bf16x8 pack8(float4 a, float4 b) {
    bf16x8 r;
    r[0] = (__bf16)a.x; r[1] = (__bf16)a.y; r[2] = (__bf16)a.z; r[3] = (__bf16)a.w;
    r[4] = (__bf16)b.x; r[5] = (__bf16)b.y; r[6] = (__bf16)b.z; r[7] = (__bf16)b.w;
    return r;
}

struct U64x2 { u64 x, y; };
__device__ __forceinline__ U64x2 sysld16(const u64* p) {
    U64x2 r;
    r.x = __hip_atomic_load(p,     __ATOMIC_RELAXED, __HIP_MEMORY_SCOPE_SYSTEM);
    r.y = __hip_atomic_load(p + 1, __ATOMIC_RELAXED, __HIP_MEMORY_SCOPE_SYSTEM);
    return r;
}
__device__ __forceinline__ void sysst8(void* p, u64 v) {
    __hip_atomic_store((u64*)p, v, __ATOMIC_RELAXED, __HIP_MEMORY_SCOPE_SYSTEM);
}
__device__ __forceinline__ u64 pack4bf(float a, float b, float c, float d) {
    union { unsigned short s[4]; u64 q; } u;
    __bf16 x0 = (__bf16)a, x1 = (__bf16)b, x2 = (__bf16)c, x3 = (__bf16)d;
    u.s[0] = __builtin_bit_cast(unsigned short, x0);
    u.s[1] = __builtin_bit_cast(unsigned short, x1);
    u.s[2] = __builtin_bit_cast(unsigned short, x2);
    u.s[3] = __builtin_bit_cast(unsigned short, x3);
    return u.q;
}
// per-batch spin barrier (16 blocks); counters padded to 256B (one MALL line each).
__device__ __forceinline__ void bbar(unsigned int* c, unsigned int target) {
    __syncthreads();
    if (threadIdx.x == 0) {
        __hip_atomic_fetch_add(c, 1u, __ATOMIC_RELAXED, __HIP_MEMORY_SCOPE_SYSTEM);
        while (__hip_atomic_load(c, __ATOMIC_RELAXED, __HIP_MEMORY_SCOPE_SYSTEM) < target)
            __builtin_amdgcn_s_sleep(1);
    }
    __syncthreads();
}

// ---------------- stage 1: fused conv1+conv2+pool, 4-way T-split ------------
__global__ __launch_bounds__(512) void s1_conv4(const float* __restrict__ ein,
        const float* __restrict__ w1, const float* __restrict__ b1c,
        const float* __restrict__ w2r, const float* __restrict__ b2c,
        float* __restrict__ f_part) {
    __shared__ float xb[1032];
    __shared__ float c1t[C1N][1012];
    __shared__ float red[512];
    int n = blockIdx.x, q = blockIdx.y, t = threadIdx.x;
    int pos0 = q * 996;
    int plen = (q < 3) ? 996 : 994;
    int xlen = plen + 18;
    for (int i = t; i < xlen; i += 512) xb[i] = ein[n * TLEN + pos0 + i];
    if (t < 14) xb[xlen + t] = 0.f;
    __syncthreads();
    int c1len = plen + 9;
    int p0 = 2 * t;
    if (p0 < c1len) {
        float xr[12];
        const float2* xp = (const float2*)&xb[p0];
#pragma unroll
        for (int qq = 0; qq < 6; qq++) { float2 v = xp[qq]; xr[2*qq] = v.x; xr[2*qq+1] = v.y; }
#pragma unroll
        for (int c = 0; c < C1N; c++) {
            float a0 = b1c[c], a1 = a0;
#pragma unroll
            for (int k = 0; k < KW; k++) {
                float wv = w1[c * KW + k];
                a0 += xr[k] * wv;
                a1 += xr[k + 1] * wv;
            }
            c1t[c][p0] = fmaxf(a0, 0.f);
            if (p0 + 1 < c1len) c1t[c][p0 + 1] = fmaxf(a1, 0.f);
        }
    }
    __syncthreads();
    f32x2 a[C2N];
#pragma unroll
    for (int c = 0; c < C2N; c++) { float bv = b2c[c]; a[c] = (f32x2){bv, bv}; }
    bool v0 = p0 < plen, v1 = p0 + 1 < plen;
    if (v0) {
        for (int c1 = 0; c1 < C1N; c1++) {
            float xr[12];
            const float2* cp = (const float2*)&c1t[c1][p0];
#pragma unroll
            for (int qq = 0; qq < 6; qq++) { float2 v = cp[qq]; xr[2*qq] = v.x; xr[2*qq+1] = v.y; }
#pragma unroll
            for (int k = 0; k < KW; k++) {
                f32x2 x01 = {xr[k], xr[k + 1]};
                const float4* wq = (const float4*)&w2r[(c1 * KW + k) * C2N];
                float4 wa = wq[0], wb = wq[1], wc = wq[2], wd = wq[3];
                a[0] += x01 * wa.x;  a[1] += x01 * wa.y;
                a[2] += x01 * wa.z;  a[3] += x01 * wa.w;
                a[4] += x01 * wb.x;  a[5] += x01 * wb.y;
                a[6] += x01 * wb.z;  a[7] += x01 * wb.w;
                a[8] += x01 * wc.x;  a[9] += x01 * wc.y;
                a[10] += x01 * wc.z; a[11] += x01 * wc.w;
                a[12] += x01 * wd.x; a[13] += x01 * wd.y;
                a[14] += x01 * wd.z; a[15] += x01 * wd.w;
            }
        }
    }
    for (int c2 = 0; c2 < C2N; c2++) {
        float s = (v0 ? fmaxf(a[c2][0], 0.f) : 0.f) + (v1 ? fmaxf(a[c2][1], 0.f) : 0.f);
        red[t] = s;
        __syncthreads();
        for (int sn = 256; sn > 0; sn >>= 1) {
            if (t < sn) red[t] += red[t + sn];
            __syncthreads();
        }
        if (t == 0) f_part[(n * 4 + q) * C2N + c2] = red[0];
        __syncthreads();
    }
}

__global__ __launch_bounds__(256) void prep_w2(const float* __restrict__ w2,
        float* __restrict__ w2r) {
    int idx = blockIdx.x * 256 + threadIdx.x;
    if (idx < C1N * KW * C2N) {
        int c2 = idx & 15, c1k = idx >> 4;
        w2r[idx] = w2[c2 * (C1N * KW) + c1k];
    }
}

// ---------------- stage 1b/1c ----------------
__global__ __launch_bounds__(128) void fc_relu(const float* __restrict__ f_part,
        const float* __restrict__ fcw, const float* __restrict__ fcb,
        float* __restrict__ f) {
    __shared__ float fr[C2N];
    int n = blockIdx.x, t = threadIdx.x;
    if (t < C2N) {
        const float* fp = f_part + n * 64 + t;
        fr[t] = (((fp[0] + fp[16]) + fp[32]) + fp[48]) / 3982.0f;
    }
    __syncthreads();
    float acc = fcb[t];
#pragma unroll
    for (int c = 0; c < C2N; c++) acc += fr[c] * fcw[c * DD + t];
    f[n * DD + t] = fmaxf(acc, 0.f);
}

__global__ __launch_bounds__(128) void fafb_k(const float* __restrict__ f,
        const float* __restrict__ Wa, const float* __restrict__ Wb,
        float* __restrict__ fa, float* __restrict__ fb) {
    __shared__ float fr[DD];
    int n = blockIdx.x, t = threadIdx.x;
    fr[t] = f[n * DD + t];
    __syncthreads();
    float a = 0.f, b = 0.f;
    for (int k = 0; k < DD; k++) {
        float fv = fr[k];
        a += fv * Wa[k * HE + t];
        b += fv * Wb[k * HE + t];
    }
    fa[n * HE + t] = a;
    fb[n * HE + t] = b;
}

// ---------------- stage 2: edge MLP + gumbel hard mask ----------
__global__ __launch_bounds__(256) void edge_mask(const float* __restrict__ fa,
        const float* __restrict__ fb, const float* __restrict__ b1,
        const float* __restrict__ W2, const float* __restrict__ b2,
        const float* __restrict__ u_noise, float* __restrict__ mask) {
    __shared__ __align__(16) float sfa[16][132], sfb[16][132];
    __shared__ __align__(16) float w20[HE], w21[HE], b1s[HE];
    __shared__ float b2s[2];
    int t = threadIdx.x;
    int i0 = blockIdx.x * 16, j0 = blockIdx.y * 16;
    for (int idx = t; idx < 16 * HE; idx += 256) {
        int r = idx >> 7, c = idx & 127;
        sfa[r][c] = (i0 + r < NN) ? fa[(i0 + r) * HE + c] : 0.f;
        sfb[r][c] = (j0 + r < NN) ? fb[(j0 + r) * HE + c] : 0.f;
    }
    if (t < HE) { w20[t] = W2[t * 2]; w21[t] = W2[t * 2 + 1]; b1s[t] = b1[t]; }
    if (t < 2) b2s[t] = b2[t];
    __syncthreads();
    int ti = t >> 4, tj = t & 15;
    int i = i0 + ti, j = j0 + tj;
    if (i >= NN || j >= NN) return;
    double l0 = 0.0, l1 = 0.0;
    for (int dd = 0; dd < HE; dd += 4) {
        float4 av = *(const float4*)&sfa[ti][dd];
        float4 bv = *(const float4*)&sfb[tj][dd];
        float4 bb = *(const float4*)&b1s[dd];
        float4 w0 = *(const float4*)&w20[dd];
        float4 w1 = *(const float4*)&w21[dd];
        float h0 = fmaxf(av.x + bv.x + bb.x, 0.f);
        l0 += (double)h0 * (double)w0.x; l1 += (double)h0 * (double)w1.x;
        float h1 = fmaxf(av.y + bv.y + bb.y, 0.f);
        l0 += (double)h1 * (double)w0.y; l1 += (double)h1 * (double)w1.y;
        float h2 = fmaxf(av.z + bv.z + bb.z, 0.f);
        l0 += (double)h2 * (double)w0.z; l1 += (double)h2 * (double)w1.z;
        float h3 = fmaxf(av.w + bv.w + bb.w, 0.f);
        l0 += (double)h3 * (double)w0.w; l1 += (double)h3 * (double)w1.w;
    }
    long e = (long)i * NN + j;
    double u0 = (double)u_noise[2 * e], u1 = (double)u_noise[2 * e + 1];
    double g0 = -log(-log(u0 + 1e-10) + 1e-10);
    double g1 = -log(-log(u1 + 1e-10) + 1e-10);
    double s0 = l0 + (double)b2s[0] + g0;
    double s1 = l1 + (double)b2s[1] + g1;
    float mv = (i == j) ? 0.f : ((s0 >= s1) ? 1.f : 0.f);
    mask[e] = mv;
}

__global__ __launch_bounds__(256) void row_deg(const float* __restrict__ mask,
        float* __restrict__ deg) {
    __shared__ float red[256];
    int i = blockIdx.x, t = threadIdx.x;
    float s = 0.f;
    for (int j = t; j < NN; j += 256) s += mask[i * NN + j];
    red[t] = s;
    __syncthreads();
    for (int w = 128; w > 0; w >>= 1) {
        if (t < w) red[t] += red[t + w];
        __syncthreads();
    }
    if (t == 0) deg[i] = red[0];
}

__global__ __launch_bounds__(256) void make_A(const float* __restrict__ mask,
        const float* __restrict__ deg, __bf16* __restrict__ A_bf) {
    int idx = blockIdx.x * 256 + threadIdx.x;
    int i = idx >> 10, j = idx & 1023;
    float v = 0.f;
    if (i < NN && j < NN) v = mask[i * NN + j] / (deg[i] + 1e-6f);
    A_bf[idx] = (__bf16)v;
}

__global__ __launch_bounds__(64) void row_sumA(const __bf16* __restrict__ A_bf,
        float* __restrict__ rs) {
    int j = blockIdx.x, l = threadIdx.x;
    const __bf16* row = A_bf + (size_t)j * 1024 + l * 16;
    float s = 0.f;
#pragma unroll
    for (int i = 0; i < 16; i++) s += (float)row[i];
#pragma unroll
    for (int off = 32; off > 0; off >>= 1) s += __shfl_xor(s, off);
    if (l == 0) rs[j] = s;
}

__global__ void init_zero(float* __restrict__ p, int n) {
    int stride = gridDim.x * blockDim.x;
    for (int i = blockIdx.x * blockDim.x + threadIdx.x; i < n; i += stride) p[i] = 0.f;
}

// ---------------- weight prep ----------------
__global__ __launch_bounds__(256) void prep_w(
        const float* __restrict__ eWru0, const float* __restrict__ eWru1,
        const float* __restrict__ eWc0,  const float* __restrict__ eWc1,
        const float* __restrict__ dWru0, const float* __restrict__ dWru1,
        const float* __restrict__ dWc0,  const float* __restrict__ dWc1,
        __bf16* __restrict__ wp) {
    int idx = blockIdx.x * 256 + threadIdx.x;
    if (idx >= 49152) return;
    int half = idx / 24576;
    int li = idx - half * 24576;
    const float* Wru0 = half ? dWru0 : eWru0;
    const float* Wru1 = half ? dWru1 : eWru1;
    const float* Wc0  = half ? dWc0  : eWc0;
    const float* Wc1  = half ? dWc1  : eWc1;
    float v;
    if (li < 16384) {
        const float* W = (li < 8192) ? Wru0 : Wru1;
        int l2 = li & 8191;
        int d = l2 >> 6, f = l2 & 63;
        v = W[(1 + f) * 128 + d];
    } else {
        int l2 = li - 16384;
        const float* W = (l2 < 4096) ? Wc0 : Wc1;
        int l3 = l2 & 4095;
        int d = l3 >> 6, f = l3 & 63;
        v = W[(1 + f) * 64 + d];
    }
    wp[idx] = (__bf16)v;
}

__global__ __launch_bounds__(256) void prep_xe(const float* __restrict__ inputs,
        __bf16* __restrict__ XeT) {
    int idx = blockIdx.x * 256 + threadIdx.x;
    int c = idx >> 10, j = idx & 1023;
    int s = c >> 4, b = c & 15;
    float v = (j < NN) ? inputs[(b * SS + s) * NN + j] : 0.f;
    XeT[c * 1024 + j] = (__bf16)v;
}

// ---------------- bf16 MFMA GEMM (aggXe) ----------------
__global__ __launch_bounds__(256) void gemm_bf(const __bf16* __restrict__ A,
        const __bf16* __restrict__ BT, float* __restrict__ C, int cstride) {
    __shared__ __align__(16) __bf16 As[2][2048];
    __shared__ __align__(16) __bf16 Bs[2][2048];
    int t = threadIdx.x;
    int bm = blockIdx.x * 64;
    int tile = blockIdx.y;
    const __bf16* Bbase = BT + tile * 65536;
    int am = t >> 2;
    int ag = ((t & 3) - (am >> 1)) & 3;
    const __bf16* agp = A + (bm + am) * 1024 + ag * 8;
    const __bf16* bgp = Bbase + am * 1024 + ag * 8;
    int w = t >> 6, l = t & 63, lr = l & 15, lh = l >> 4;
    int ldso = t * 8;
    f32x4 acc[4];
#pragma unroll
    for (int i = 0; i < 4; i++) acc[i] = (f32x4){0.f, 0.f, 0.f, 0.f};

    glds16(agp, &As[0][ldso]);
    glds16(bgp, &Bs[0][ldso]);
    __syncthreads();
    int cur = 0;
    for (int it = 0; it < 32; ++it) {
        if (it < 31) {
            glds16(agp + (it + 1) * 32, &As[cur ^ 1][ldso]);
            glds16(bgp + (it + 1) * 32, &Bs[cur ^ 1][ldso]);
        }
        int arow = w * 16 + lr;
        int asw = (lh + (arow >> 1)) & 3;
        bf16x8 af = *(const bf16x8*)&As[cur][arow * 32 + asw * 8];
#pragma unroll
        for (int ct = 0; ct < 4; ++ct) {
            int nrow = ct * 16 + lr;
            int bsw = (lh + (nrow >> 1)) & 3;
            bf16x8 bv = *(const bf16x8*)&Bs[cur][nrow * 32 + bsw * 8];
            acc[ct] = __builtin_amdgcn_mfma_f32_16x16x32_bf16(af, bv, acc[ct], 0, 0, 0);
        }
        __syncthreads();
        cur ^= 1;
    }
#pragma unroll
    for (int ct = 0; ct < 4; ++ct)
#pragma unroll
        for (int r = 0; r < 4; ++r) {
            int m_loc = w * 16 + lh * 4 + r;
            C[(bm + m_loc) * cstride + tile * 64 + ct * 16 + lr] = acc[ct][r];
        }
}

// ---------------- persistent recurrence (A in regs, full B preload) ---------
struct RA {
    const __bf16 *A;
    const __bf16 *W0Te, *W1Te, *Wc0Te, *Wc1Te;
    const __bf16 *W0Td, *W1Td, *Wc0Td, *Wc1Td;
    float *h32;
    __bf16 *HbT, *RHbT;
    float *ubuf;
    const float *inputs, *aggXe, *rowsum;
    const float *eWru0, *eWru1, *ebru, *eWc0, *eWc1, *ebc;
    const float *dWru0, *dWru1, *dbru, *dWc0, *dWc1, *dbc;
    const float *projw, *projb;
    float *outputs;
    unsigned int *ctr;
};

__global__ __launch_bounds__(512, 2) void recur(RA a) {
    __shared__ __align__(16) __bf16 Bs[2][4096];
    __shared__ __align__(16) __bf16 Ag[4096];
    __shared__ __align__(16) __bf16 RHs[4096];
    __shared__ float xs[64], axs[64], w0x[128], w1x[128], bbs[128], pws[64];
    __shared__ float pp[2][64];
    int t = threadIdx.x;
    int bid = blockIdx.x;
    int b = bid & 15, jb = bid >> 4;
    int bm = jb * 64;
    unsigned int* ctr = a.ctr + b * 64;        // 256B-padded counters
    if (t < 64) pws[t] = a.projw[t];
    float pb = a.projb[0];
    int r64 = t >> 3, s8 = t & 7;
    int gc = (s8 - r64) & 7;
    int ldso = t * 8;
    int w = t >> 6, l = t & 63, lr = l & 15, lh = l >> 4;
    int wr = w & 3, wc = w >> 2;
    int arow = wr * 16 + lr;
    unsigned int phase = 0;

    // ---- A operand fragments: loaded once, pinned in VGPRs for all 48 phases
    bf16x8 Areg[16][2];
    {
        const __bf16* arp = a.A + (size_t)(bm + arow) * 1024 + lh * 8;
#pragma unroll
        for (int it = 0; it < 16; ++it) {
            Areg[it][0] = *(const bf16x8*)(arp + it * 64);
            Areg[it][1] = *(const bf16x8*)(arp + it * 64 + 32);
        }
    }
    __syncthreads();

    for (int step = 0; step < SS + HH; ++step) {
        bool dec = step >= SS;
        // ===================== PHASE 1 (r,u gate) =====================
        {
            const __bf16* W0T = dec ? a.W0Td : a.W0Te;
            const __bf16* W1T = dec ? a.W1Td : a.W1Te;
            const float* Wru0 = dec ? a.dWru0 : a.eWru0;
            const float* Wru1 = dec ? a.dWru1 : a.eWru1;
            const float* bru  = dec ? a.dbru  : a.ebru;
            // ---- B slice (HbT) full preload: 16 x 16B system-scope loads ----
            const u64* gpbq = (const u64*)(a.HbT + (size_t)(b * 64 + r64) * 1024 + gc * 8);
            U64x2 P[16];
#pragma unroll
            for (int i = 0; i < 16; ++i) P[i] = sysld16(gpbq + i * 16);
            if (t < 64) {
                int j = bm + t;
                if (!dec) {
                    xs[t] = (j < NN) ? a.inputs[(b * SS + step) * NN + j] : 0.f;
                    axs[t] = a.aggXe[j * 192 + step * 16 + b];
                } else if (step == SS) {
                    xs[t] = 0.f; axs[t] = 0.f;     // decoder y0 = 0
                } else {
                    const float* hp = a.h32 + ((size_t)(j * 16 + b)) * 64;
                    float acc = 0.f;
#pragma unroll
                    for (int d2 = 0; d2 < 64; d2 += 4) {
                        float4 v = *(const float4*)(hp + d2);
                        acc += v.x * pws[d2] + v.y * pws[d2 + 1]
                             + v.z * pws[d2 + 2] + v.w * pws[d2 + 3];
                    }
                    xs[t] = acc + pb;              // y_prev = proj(h)
                }
            } else if (t < 192) {
                int d = t - 64;
                w0x[d] = Wru0[d]; w1x[d] = Wru1[d]; bbs[d] = bru[d];
            }
            f32x4 acc0 = (f32x4){0.f, 0.f, 0.f, 0.f};
            f32x4 acc1 = (f32x4){0.f, 0.f, 0.f, 0.f};
            ((u64*)&Bs[0][ldso])[0] = P[0].x;
            ((u64*)&Bs[0][ldso])[1] = P[0].y;
            __syncthreads();
#pragma unroll
            for (int it = 0; it < 16; ++it) {
                int cur = it & 1;
#pragma unroll
                for (int kk = 0; kk < 2; ++kk) {
                    int ca = kk * 4 + lh;
                    bf16x8 af = Areg[it][kk];
                    int n0 = wc * 32 + lr;
                    bf16x8 bv0 = *(const bf16x8*)&Bs[cur][n0 * 64 + (((ca + n0) & 7) << 3)];
                    acc0 = __builtin_amdgcn_mfma_f32_16x16x32_bf16(af, bv0, acc0, 0, 0, 0);
                    int n1 = n0 + 16;
                    bf16x8 bv1 = *(const bf16x8*)&Bs[cur][n1 * 64 + (((ca + n1) & 7) << 3)];
                    acc1 = __builtin_amdgcn_mfma_f32_16x16x32_bf16(af, bv1, acc1, 0, 0, 0);
                }
                if (it < 15) {
                    ((u64*)&Bs[cur ^ 1][ldso])[0] = P[it + 1].x;
                    ((u64*)&Bs[cur ^ 1][ldso])[1] = P[it + 1].y;
                }
                __syncthreads();
            }
            {
                f32x4 acc[2] = {acc0, acc1};
#pragma unroll
                for (int ct = 0; ct < 2; ++ct)
#pragma unroll
                    for (int r = 0; r < 4; ++r) {
                        int m = wr * 16 + lh * 4 + r;
                        int d = wc * 32 + ct * 16 + lr;
                        Ag[m * 64 + ((((d >> 3) + m) & 7) << 3) + (d & 7)] = (__bf16)acc[ct][r];
                    }
            }
            __syncthreads();
            // decoder: axs = (A@H)·pw + pb·rowsum == A @ y_prev
            if (dec && step > SS && t < 64) {
                float accx = 0.f;
#pragma unroll
                for (int seg = 0; seg < 8; ++seg) {
                    const __bf16* ap = &Ag[t * 64 + (((seg + t) & 7) << 3)];
#pragma unroll
                    for (int q = 0; q < 8; q++) accx += (float)ap[q] * pws[seg * 8 + q];
                }
                axs[t] = accx + pb * a.rowsum[bm + t];
            }
            // ---- gate GEMM: K=64(h)+64(agg), N=128; W frags direct global --
            f32x4 g[4];
#pragma unroll
            for (int i = 0; i < 4; i++) g[i] = (f32x4){0.f, 0.f, 0.f, 0.f};
            const float* hrow = a.h32 + ((size_t)((bm + arow) * 16 + b)) * 64;
#pragma unroll
            for (int h2 = 0; h2 < 2; ++h2) {
                float4 hv0 = *(const float4*)(hrow + h2 * 32 + lh * 8);
                float4 hv1 = *(const float4*)(hrow + h2 * 32 + lh * 8 + 4);
                bf16x8 ah = pack8(hv0, hv1);
                int sega = h2 * 4 + lh;
                bf16x8 agf = *(const bf16x8*)&Ag[arow * 64 + (((sega + arow) & 7) << 3)];
#pragma unroll
                for (int ct = 0; ct < 4; ++ct) {
                    int n = wc * 64 + ct * 16 + lr;
                    bf16x8 w0f = *(const bf16x8*)&W0T[n * 64 + sega * 8];
                    bf16x8 w1f = *(const bf16x8*)&W1T[n * 64 + sega * 8];
                    g[ct] = __builtin_amdgcn_mfma_f32_16x16x32_bf16(ah, w0f, g[ct], 0, 0, 0);
                    g[ct] = __builtin_amdgcn_mfma_f32_16x16x32_bf16(agf, w1f, g[ct], 0, 0, 0);
                }
            }
            __syncthreads();   // axs ready
#pragma unroll
            for (int ct = 0; ct < 4; ++ct) {
                int d = wc * 64 + ct * 16 + lr;
                float rh4[4];
#pragma unroll
                for (int r = 0; r < 4; ++r) {
                    int m = wr * 16 + lh * 4 + r;
                    int j = bm + m;
                    size_t mg = (size_t)(j * 16 + b);
                    float pre = g[ct][r] + xs[m] * w0x[d] + axs[m] * w1x[d] + bbs[d];
                    float sg = 1.f / (1.f + expf(-pre));
                    if (d < 64) {
                        float rh = sg * a.h32[mg * 64 + d];
                        RHs[m * 64 + ((((d >> 3) + m) & 7) << 3) + (d & 7)] = (__bf16)rh;
                        rh4[r] = rh;
                    } else {
                        a.ubuf[mg * 64 + (d - 64)] = sg;   // block-private
                    }
                }
                if (d < 64)
                    sysst8(&a.RHbT[((size_t)(b * 64 + d)) * 1024 + bm + wr * 16 + lh * 4],
                           pack4bf(rh4[0], rh4[1], rh4[2], rh4[3]));
            }
        }
        bbar(ctr, 16u * (++phase));
        // ===================== PHASE 2 (candidate + update) =====================
        {
            const __bf16* WcT0 = dec ? a.Wc0Td : a.Wc0Te;
            const __bf16* WcT1 = dec ? a.Wc1Td : a.Wc1Te;
            const float* Wc0 = dec ? a.dWc0 : a.eWc0;
            const float* Wc1 = dec ? a.dWc1 : a.eWc1;
            const float* bc  = dec ? a.dbc  : a.ebc;
            const u64* gpbq = (const u64*)(a.RHbT + (size_t)(b * 64 + r64) * 1024 + gc * 8);
            U64x2 P[16];
#pragma unroll
            for (int i = 0; i < 16; ++i) P[i] = sysld16(gpbq + i * 16);
            if (t >= 64 && t < 128) {
                int d = t - 64;
                w0x[d] = Wc0[d]; w1x[d] = Wc1[d]; bbs[d] = bc[d];
            }
            f32x4 acc0 = (f32x4){0.f, 0.f, 0.f, 0.f};
            f32x4 acc1 = (f32x4){0.f, 0.f, 0.f, 0.f};
            ((u64*)&Bs[0][ldso])[0] = P[0].x;
            ((u64*)&Bs[0][ldso])[1] = P[0].y;
            __syncthreads();
#pragma unroll
            for (int it = 0; it < 16; ++it) {
                int cur = it & 1;
#pragma unroll
                for (int kk = 0; kk < 2; ++kk) {
                    int ca = kk * 4 + lh;
                    bf16x8 af = Areg[it][kk];
                    int n0 = wc * 32 + lr;
                    bf16x8 bv0 = *(const bf16x8*)&Bs[cur][n0 * 64 + (((ca + n0) & 7) << 3)];
                    acc0 = __builtin_amdgcn_mfma_f32_16x16x32_bf16(af, bv0, acc0, 0, 0, 0);
                    int n1 = n0 + 16;
                    bf16x8 bv1 = *(const bf16x8*)&Bs[cur][n1 * 64 + (((ca + n1) & 7) << 3)];
                    acc1 = __builtin_amdgcn_mfma_f32_16x16x32_bf16(af, bv1, acc1, 0, 0, 0);
                }
                if (it < 15) {
                    ((u64*)&Bs[cur ^ 1][ldso])[0] = P[it + 1].x;
                    ((u64*)&Bs[cur ^ 1][ldso])[1] = P[it + 1].y;
                }
                __syncthreads();
            }
            {
                f32x4 acc[2] = {acc0, acc1};
#pragma unroll
                for (int ct = 0; ct < 2; ++ct)
#pragma unroll
                    for (int r = 0; r < 4; ++r) {
                        int m = wr * 16 + lh * 4 + r;
                        int d = wc * 32 + ct * 16 + lr;
                        Ag[m * 64 + ((((d >> 3) + m) & 7) << 3) + (d & 7)] = (__bf16)acc[ct][r];
                    }
            }
            __syncthreads();
            // ---- gate GEMM: N=64; A-operands from LDS (RHs, Ag) ----
            f32x4 g[2];
            g[0] = (f32x4){0.f, 0.f, 0.f, 0.f};
            g[1] = (f32x4){0.f, 0.f, 0.f, 0.f};
#pragma unroll
            for (int h2 = 0; h2 < 2; ++h2) {
                int sega = h2 * 4 + lh;
                int aslot = arow * 64 + (((sega + arow) & 7) << 3);
                bf16x8 ah = *(const bf16x8*)&RHs[aslot];
                bf16x8 agf = *(const bf16x8*)&Ag[aslot];
#pragma unroll
                for (int ct = 0; ct < 2; ++ct) {
                    int n = wc * 32 + ct * 16 + lr;
                    bf16x8 w0f = *(const bf16x8*)&WcT0[n * 64 + sega * 8];
                    bf16x8 w1f = *(const bf16x8*)&WcT1[n * 64 + sega * 8];
                    g[ct] = __builtin_amdgcn_mfma_f32_16x16x32_bf16(ah, w0f, g[ct], 0, 0, 0);
                    g[ct] = __builtin_amdgcn_mfma_f32_16x16x32_bf16(agf, w1f, g[ct], 0, 0, 0);
                }
            }
            float part[4] = {0.f, 0.f, 0.f, 0.f};
#pragma unroll
            for (int ct = 0; ct < 2; ++ct) {
                int d = wc * 32 + ct * 16 + lr;
                float hn4[4];
#pragma unroll
                for (int r = 0; r < 4; ++r) {
                    int m = wr * 16 + lh * 4 + r;
                    int j = bm + m;
                    size_t mg = (size_t)(j * 16 + b);
                    float pre = g[ct][r] + xs[m] * w0x[d] + axs[m] * w1x[d] + bbs[d];
                    float cv = tanhf(pre);
                    float u = a.ubuf[mg * 64 + d];
                    float hold = a.h32[mg * 64 + d];
                    float hn = u * hold + (1.f - u) * cv;
                    a.h32[mg * 64 + d] = hn;       // block-private
                    hn4[r] = hn;
                    if (dec) part[r] += hn * pws[d];
                }
                sysst8(&a.HbT[((size_t)(b * 64 + d)) * 1024 + bm + wr * 16 + lh * 4],
                       pack4bf(hn4[0], hn4[1], hn4[2], hn4[3]));
            }
            if (dec) {
#pragma unroll
                for (int r = 0; r < 4; ++r) {
#pragma unroll
                    for (int off = 1; off < 16; off <<= 1)
                        part[r] += __shfl_xor(part[r], off);
                }
                if (lr == 0) {
#pragma unroll
                    for (int r = 0; r < 4; ++r) pp[wc][wr * 16 + lh * 4 + r] = part[r];
                }
                __syncthreads();
                if (t < 64) {
                    float y = pp[0][t] + pp[1][t] + pb;
                    int j = bm + t;
                    if (j < NN) a.outputs[(b * HH + (step - SS)) * NN + j] = y;
                }
            }
        }
        bbar(ctr, 16u * (++phase));
    }
}

// ---------------- loss ----------------
__global__ __launch_bounds__(256) void loss1(const float* __restrict__ outs,
        const float* __restrict__ tgt, float* __restrict__ part) {
    __shared__ float red[256];
    int t = blockIdx.x * 256 + threadIdx.x;
    float s = 0.f;
    for (int i = t; i < BB * HH * NN; i += 256 * 256) {
        float dd = outs[i] - tgt[i];
        s += dd * dd;
    }
    red[threadIdx.x] = s;
    __syncthreads();
    for (int w = 128; w > 0; w >>= 1) {
        if (threadIdx.x < w) red[threadIdx.x] += red[threadIdx.x + w];
        __syncthreads();
    }
    if (threadIdx.x == 0) part[blockIdx.x] = red[0];
}

__global__ __launch_bounds__(256) void loss2(const float* __restrict__ part,
        float* __restrict__ loss) {
    __shared__ double red[256];
    int t = threadIdx.x;
    red[t] = (double)part[t];
    __syncthreads();
    for (int w = 128; w > 0; w >>= 1) {
        if (t < w) red[t] += red[t + w];
        __syncthreads();
    }
    if (t == 0) loss[0] = (float)(red[0] / (double)(BB * HH * NN));
}

// ---------------- host ----------------
extern "C" void kernel_launch(void* const* d_in, const int* in_sizes, int n_in,
                              void* d_out, int out_size, void* d_ws, size_t ws_size,
                              hipStream_t stream) {
    const float* inputs  = (const float*)d_in[0];
    const float* ein     = (const float*)d_in[1];
    const float* targets = (const float*)d_in[2];
    const float* u_noise = (const float*)d_in[3];
    const float* c1w = (const float*)d_in[4];
    const float* c1b = (const float*)d_in[5];
    const float* c2w = (const float*)d_in[6];
    const float* c2b = (const float*)d_in[7];
    const float* fcw = (const float*)d_in[8];
    const float* fcb = (const float*)d_in[9];
    const float* Wa  = (const float*)d_in[10];
    const float* Wb  = (const float*)d_in[11];
    const float* b1  = (const float*)d_in[12];
    const float* W2  = (const float*)d_in[13];
    const float* b2  = (const float*)d_in[14];
    const float* eWru0 = (const float*)d_in[15];
    const float* eWru1 = (const float*)d_in[16];
    const float* ebru  = (const float*)d_in[17];
    const float* eWc0  = (const float*)d_in[18];
    const float* eWc1  = (const float*)d_in[19];
    const float* ebc   = (const float*)d_in[20];
    const float* dWru0 = (const float*)d_in[21];
    const float* dWru1 = (const float*)d_in[22];
    const float* dbru  = (const float*)d_in[23];
    const float* dWc0  = (const float*)d_in[24];
    const float* dWc1  = (const float*)d_in[25];
    const float* dbc   = (const float*)d_in[26];
    const float* projw = (const float*)d_in[27];
    const float* projb = (const float*)d_in[28];

    float* out = (float*)d_out;
    float* mask    = out;
    float* outputs = out + NN * NN;
    float* loss    = out + NN * NN + BB * HH * NN;

    float* ws = (float*)d_ws;
    float*  f_part = ws;                          // 64,000
    float*  fbuf   = ws + 64000;                  // 128,000
    float*  fa     = ws + 192000;                 // 128,000
    float*  fb     = ws + 320000;                 // 128,000
    float*  deg    = ws + 448000;                 // 1,024
    float*  lossp  = ws + 449024;                 // 256
    float*  rowsum = ws + 449280;                 // 1,024
    float*  w2r    = ws + 450304;                 // 1,280
    __bf16* wp     = (__bf16*)(ws + 451584);      // 49,152 bf16
    __bf16* A_bf   = (__bf16*)(ws + 476160);      // 1,048,576 bf16
    __bf16* XeT    = (__bf16*)(ws + 1000448);     // 196,608 bf16
    float*  aggXe  = ws + 1098752;                // 196,608 f32
    __bf16* RHbT   = (__bf16*)(ws + 1295360);     // 1,048,576 bf16
    float*  ubuf   = ws + 1819648;                // 1,048,576 f32
    float*  h32    = ws + 2868224;                // 1,048,576 f32  <- zero region
    __bf16* HbT    = (__bf16*)(ws + 3916800);     // 1,048,576 bf16 <- zero region
    unsigned int* ctr = (unsigned int*)(ws + 4441088);  // 1024 u32 (16 x 256B) <- zero region
    const int ZLEN = 1048576 + 524288 + 1024;

    __bf16 *eW0T = wp, *eW1T = wp + 8192, *eWc0T = wp + 16384, *eWc1T = wp + 20480;
    __bf16 *dW0T = wp + 24576, *dW1T = wp + 32768, *dWc0T = wp + 40960, *dWc1T = wp + 45056;

    init_zero<<<2048, 256, 0, stream>>>(h32, ZLEN);
    prep_w<<<192, 256, 0, stream>>>(eWru0, eWru1, eWc0, eWc1, dWru0, dWru1, dWc0, dWc1, wp);
    prep_w2<<<5, 256, 0, stream>>>(c2w, w2r);
    prep_xe<<<768, 256, 0, stream>>>(inputs, XeT);

    // graph head
    s1_conv4<<<dim3(NN, 4), 512, 0, stream>>>(ein, c1w, c1b, w2r, c2b, f_part);
    fc_relu<<<NN, 128, 0, stream>>>(f_part, fcw, fcb, fbuf);
    fafb_k<<<NN, 128, 0, stream>>>(fbuf, Wa, Wb, fa, fb);
    edge_mask<<<dim3(63, 63), 256, 0, stream>>>(fa, fb, b1, W2, b2, u_noise, mask);
    row_deg<<<NN, 256, 0, stream>>>(mask, deg);
    make_A<<<4096, 256, 0, stream>>>(mask, deg, A_bf);
    row_sumA<<<1024, 64, 0, stream>>>(A_bf, rowsum);

    // x-aggregation for all encoder steps
    gemm_bf<<<dim3(16, 3), 256, 0, stream>>>(A_bf, XeT, aggXe, 192);

    // persistent recurrence (cooperative: co-residency for per-batch barriers)
    RA ra;
    ra.A = A_bf;
    ra.W0Te = eW0T; ra.W1Te = eW1T; ra.Wc0Te = eWc0T; ra.Wc1Te = eWc1T;
    ra.W0Td = dW0T; ra.W1Td = dW1T; ra.Wc0Td = dWc0T; ra.Wc1Td = dWc1T;
    ra.h32 = h32; ra.HbT = HbT; ra.RHbT = RHbT; ra.ubuf = ubuf;
    ra.inputs = inputs; ra.aggXe = aggXe; ra.rowsum = rowsum;
    ra.eWru0 = eWru0; ra.eWru1 = eWru1; ra.ebru = ebru;
    ra.eWc0 = eWc0; ra.eWc1 = eWc1; ra.ebc = ebc;
    ra.dWru0 = dWru0; ra.dWru1 = dWru1; ra.dbru = dbru;
    ra.dWc0 = dWc0; ra.dWc1 = dWc1; ra.dbc = dbc;
    ra.projw = projw; ra.projb = projb;
    ra.outputs = outputs;
    ra.ctr = ctr;
    void* args[] = {&ra};
    hipLaunchCooperativeKernel((const void*)recur, dim3(256), dim3(512), args, 0, stream);

    loss1<<<256, 256, 0, stream>>>(outputs, targets, lossp);
    loss2<<<1, 256, 0, stream>>>(lossp, loss);
}

// Round 9
// 921.202 us; speedup vs baseline: 1.5848x; 1.5848x over previous
//
#include <hip/hip_runtime.h>
#include <math.h>

// ---------------- problem constants ----------------
#define NN      1000
#define TLEN    4000
#define BB      16
#define SS      12
#define HH      12
#define HID     64
#define C1N     8
#define C2N     16
#define KW      10
#define L1LEN   3991
#define L2LEN   3982
#define DD      128
#define HE      128

typedef __bf16 bf16x8 __attribute__((ext_vector_type(8)));
typedef float  f32x4  __attribute__((ext_vector_type(4)));
typedef float  f32x2  __attribute__((ext_vector_type(2)));
typedef unsigned long long u64;
typedef __attribute__((address_space(3))) unsigned int       as3_u32;
typedef const __attribute__((address_space(1))) unsigned int as1_u32;

__device__ __forceinline__ void glds16(const void* g, void* l) {
    __builtin_amdgcn_global_load_lds((as1_u32*)g, (as3_u32*)l, 16, 0, 0);
}

__device__ __forceinline__ bf16x8 pack8(const float* p) {
    float4 a = *(const float4*)p, b = *(const float4*)(p + 4);
    bf16x8 r;
    r[0] = (__bf16)a.x; r[1] = (__bf16)a.y; r[2] = (__bf16)a.z; r[3] = (__bf16)a.w;
    r[4] = (__bf16)b.x; r[5] = (__bf16)b.y; r[6] = (__bf16)b.z; r[7] = (__bf16)b.w;
    return r;
}

struct U64x2 { u64 x, y; };
__device__ __forceinline__ U64x2 sysld16(const u64* p) {
    U64x2 r;
    r.x = __hip_atomic_load(p,     __ATOMIC_RELAXED, __HIP_MEMORY_SCOPE_SYSTEM);
    r.y = __hip_atomic_load(p + 1, __ATOMIC_RELAXED, __HIP_MEMORY_SCOPE_SYSTEM);
    return r;
}
__device__ __forceinline__ void sysst8(void* p, u64 v) {
    __hip_atomic_store((u64*)p, v, __ATOMIC_RELAXED, __HIP_MEMORY_SCOPE_SYSTEM);
}
__device__ __forceinline__ u64 pack4bf(float a, float b, float c, float d) {
    union { unsigned short s[4]; u64 q; } u;
    __bf16 x0 = (__bf16)a, x1 = (__bf16)b, x2 = (__bf16)c, x3 = (__bf16)d;
    u.s[0] = __builtin_bit_cast(unsigned short, x0);
    u.s[1] = __builtin_bit_cast(unsigned short, x1);
    u.s[2] = __builtin_bit_cast(unsigned short, x2);
    u.s[3] = __builtin_bit_cast(unsigned short, x3);
    return u.q;
}
// per-batch spin barrier (16 blocks); counters 256B apart (one MALL line each).
__device__ __forceinline__ void bbar(unsigned int* c, unsigned int target) {
    __syncthreads();
    if (threadIdx.x == 0) {
        __hip_atomic_fetch_add(c, 1u, __ATOMIC_RELAXED, __HIP_MEMORY_SCOPE_SYSTEM);
        while (__hip_atomic_load(c, __ATOMIC_RELAXED, __HIP_MEMORY_SCOPE_SYSTEM) < target)
            __builtin_amdgcn_s_sleep(1);
    }
    __syncthreads();
}

// ---------------- stage 1: fused conv1+conv2+pool, 4-way T-split ------------
__global__ __launch_bounds__(512) void s1_conv4(const float* __restrict__ ein,
        const float* __restrict__ w1, const float* __restrict__ b1c,
        const float* __restrict__ w2r, const float* __restrict__ b2c,
        float* __restrict__ f_part) {
    __shared__ float xb[1032];
    __shared__ float c1t[C1N][1012];
    __shared__ float red[512];
    int n = blockIdx.x, q = blockIdx.y, t = threadIdx.x;
    int pos0 = q * 996;
    int plen = (q < 3) ? 996 : 994;
    int xlen = plen + 18;
    for (int i = t; i < xlen; i += 512) xb[i] = ein[n * TLEN + pos0 + i];
    if (t < 14) xb[xlen + t] = 0.f;
    __syncthreads();
    int c1len = plen + 9;
    int p0 = 2 * t;
    if (p0 < c1len) {
        float xr[12];
        const float2* xp = (const float2*)&xb[p0];
#pragma unroll
        for (int qq = 0; qq < 6; qq++) { float2 v = xp[qq]; xr[2*qq] = v.x; xr[2*qq+1] = v.y; }
#pragma unroll
        for (int c = 0; c < C1N; c++) {
            float a0 = b1c[c], a1 = a0;
#pragma unroll
            for (int k = 0; k < KW; k++) {
                float wv = w1[c * KW + k];
                a0 += xr[k] * wv;
                a1 += xr[k + 1] * wv;
            }
            c1t[c][p0] = fmaxf(a0, 0.f);
            if (p0 + 1 < c1len) c1t[c][p0 + 1] = fmaxf(a1, 0.f);
        }
    }
    __syncthreads();
    f32x2 a[C2N];
#pragma unroll
    for (int c = 0; c < C2N; c++) { float bv = b2c[c]; a[c] = (f32x2){bv, bv}; }
    bool v0 = p0 < plen, v1 = p0 + 1 < plen;
    if (v0) {
        for (int c1 = 0; c1 < C1N; c1++) {
            float xr[12];
            const float2* cp = (const float2*)&c1t[c1][p0];
#pragma unroll
            for (int qq = 0; qq < 6; qq++) { float2 v = cp[qq]; xr[2*qq] = v.x; xr[2*qq+1] = v.y; }
#pragma unroll
            for (int k = 0; k < KW; k++) {
                f32x2 x01 = {xr[k], xr[k + 1]};
                const float4* wq = (const float4*)&w2r[(c1 * KW + k) * C2N];
                float4 wa = wq[0], wb = wq[1], wc = wq[2], wd = wq[3];
                a[0] += x01 * wa.x;  a[1] += x01 * wa.y;
                a[2] += x01 * wa.z;  a[3] += x01 * wa.w;
                a[4] += x01 * wb.x;  a[5] += x01 * wb.y;
                a[6] += x01 * wb.z;  a[7] += x01 * wb.w;
                a[8] += x01 * wc.x;  a[9] += x01 * wc.y;
                a[10] += x01 * wc.z; a[11] += x01 * wc.w;
                a[12] += x01 * wd.x; a[13] += x01 * wd.y;
                a[14] += x01 * wd.z; a[15] += x01 * wd.w;
            }
        }
    }
    for (int c2 = 0; c2 < C2N; c2++) {
        float s = (v0 ? fmaxf(a[c2][0], 0.f) : 0.f) + (v1 ? fmaxf(a[c2][1], 0.f) : 0.f);
        red[t] = s;
        __syncthreads();
        for (int sn = 256; sn > 0; sn >>= 1) {
            if (t < sn) red[t] += red[t + sn];
            __syncthreads();
        }
        if (t == 0) f_part[(n * 4 + q) * C2N + c2] = red[0];
        __syncthreads();
    }
}

__global__ __launch_bounds__(256) void prep_w2(const float* __restrict__ w2,
        float* __restrict__ w2r) {
    int idx = blockIdx.x * 256 + threadIdx.x;
    if (idx < C1N * KW * C2N) {
        int c2 = idx & 15, c1k = idx >> 4;
        w2r[idx] = w2[c2 * (C1N * KW) + c1k];
    }
}

// ---------------- stage 1b/1c ----------------
__global__ __launch_bounds__(128) void fc_relu(const float* __restrict__ f_part,
        const float* __restrict__ fcw, const float* __restrict__ fcb,
        float* __restrict__ f) {
    __shared__ float fr[C2N];
    int n = blockIdx.x, t = threadIdx.x;
    if (t < C2N) {
        const float* fp = f_part + n * 64 + t;
        fr[t] = (((fp[0] + fp[16]) + fp[32]) + fp[48]) / 3982.0f;
    }
    __syncthreads();
    float acc = fcb[t];
#pragma unroll
    for (int c = 0; c < C2N; c++) acc += fr[c] * fcw[c * DD + t];
    f[n * DD + t] = fmaxf(acc, 0.f);
}

__global__ __launch_bounds__(128) void fafb_k(const float* __restrict__ f,
        const float* __restrict__ Wa, const float* __restrict__ Wb,
        float* __restrict__ fa, float* __restrict__ fb) {
    __shared__ float fr[DD];
    int n = blockIdx.x, t = threadIdx.x;
    fr[t] = f[n * DD + t];
    __syncthreads();
    float a = 0.f, b = 0.f;
    for (int k = 0; k < DD; k++) {
        float fv = fr[k];
        a += fv * Wa[k * HE + t];
        b += fv * Wb[k * HE + t];
    }
    fa[n * HE + t] = a;
    fb[n * HE + t] = b;
}

// ---------------- stage 2: edge MLP + gumbel hard mask ----------
__global__ __launch_bounds__(256) void edge_mask(const float* __restrict__ fa,
        const float* __restrict__ fb, const float* __restrict__ b1,
        const float* __restrict__ W2, const float* __restrict__ b2,
        const float* __restrict__ u_noise, float* __restrict__ mask) {
    __shared__ __align__(16) float sfa[16][132], sfb[16][132];
    __shared__ __align__(16) float w20[HE], w21[HE], b1s[HE];
    __shared__ float b2s[2];
    int t = threadIdx.x;
    int i0 = blockIdx.x * 16, j0 = blockIdx.y * 16;
    for (int idx = t; idx < 16 * HE; idx += 256) {
        int r = idx >> 7, c = idx & 127;
        sfa[r][c] = (i0 + r < NN) ? fa[(i0 + r) * HE + c] : 0.f;
        sfb[r][c] = (j0 + r < NN) ? fb[(j0 + r) * HE + c] : 0.f;
    }
    if (t < HE) { w20[t] = W2[t * 2]; w21[t] = W2[t * 2 + 1]; b1s[t] = b1[t]; }
    if (t < 2) b2s[t] = b2[t];
    __syncthreads();
    int ti = t >> 4, tj = t & 15;
    int i = i0 + ti, j = j0 + tj;
    if (i >= NN || j >= NN) return;
    double l0 = 0.0, l1 = 0.0;
    for (int dd = 0; dd < HE; dd += 4) {
        float4 av = *(const float4*)&sfa[ti][dd];
        float4 bv = *(const float4*)&sfb[tj][dd];
        float4 bb = *(const float4*)&b1s[dd];
        float4 w0 = *(const float4*)&w20[dd];
        float4 w1 = *(const float4*)&w21[dd];
        float h0 = fmaxf(av.x + bv.x + bb.x, 0.f);
        l0 += (double)h0 * (double)w0.x; l1 += (double)h0 * (double)w1.x;
        float h1 = fmaxf(av.y + bv.y + bb.y, 0.f);
        l0 += (double)h1 * (double)w0.y; l1 += (double)h1 * (double)w1.y;
        float h2 = fmaxf(av.z + bv.z + bb.z, 0.f);
        l0 += (double)h2 * (double)w0.z; l1 += (double)h2 * (double)w1.z;
        float h3 = fmaxf(av.w + bv.w + bb.w, 0.f);
        l0 += (double)h3 * (double)w0.w; l1 += (double)h3 * (double)w1.w;
    }
    long e = (long)i * NN + j;
    double u0 = (double)u_noise[2 * e], u1 = (double)u_noise[2 * e + 1];
    double g0 = -log(-log(u0 + 1e-10) + 1e-10);
    double g1 = -log(-log(u1 + 1e-10) + 1e-10);
    double s0 = l0 + (double)b2s[0] + g0;
    double s1 = l1 + (double)b2s[1] + g1;
    float mv = (i == j) ? 0.f : ((s0 >= s1) ? 1.f : 0.f);
    mask[e] = mv;
}

__global__ __launch_bounds__(256) void row_deg(const float* __restrict__ mask,
        float* __restrict__ deg) {
    __shared__ float red[256];
    int i = blockIdx.x, t = threadIdx.x;
    float s = 0.f;
    for (int j = t; j < NN; j += 256) s += mask[i * NN + j];
    red[t] = s;
    __syncthreads();
    for (int w = 128; w > 0; w >>= 1) {
        if (t < w) red[t] += red[t + w];
        __syncthreads();
    }
    if (t == 0) deg[i] = red[0];
}

__global__ __launch_bounds__(256) void make_A(const float* __restrict__ mask,
        const float* __restrict__ deg, __bf16* __restrict__ A_bf) {
    int idx = blockIdx.x * 256 + threadIdx.x;
    int i = idx >> 10, j = idx & 1023;
    float v = 0.f;
    if (i < NN && j < NN) v = mask[i * NN + j] / (deg[i] + 1e-6f);
    A_bf[idx] = (__bf16)v;
}

__global__ __launch_bounds__(64) void row_sumA(const __bf16* __restrict__ A_bf,
        float* __restrict__ rs) {
    int j = blockIdx.x, l = threadIdx.x;
    const __bf16* row = A_bf + (size_t)j * 1024 + l * 16;
    float s = 0.f;
#pragma unroll
    for (int i = 0; i < 16; i++) s += (float)row[i];
#pragma unroll
    for (int off = 32; off > 0; off >>= 1) s += __shfl_xor(s, off);
    if (l == 0) rs[j] = s;
}

__global__ void init_zero(float* __restrict__ p, int n) {
    int stride = gridDim.x * blockDim.x;
    for (int i = blockIdx.x * blockDim.x + threadIdx.x; i < n; i += stride) p[i] = 0.f;
}

// ---------------- weight prep ----------------
__global__ __launch_bounds__(256) void prep_w(
        const float* __restrict__ eWru0, const float* __restrict__ eWru1,
        const float* __restrict__ eWc0,  const float* __restrict__ eWc1,
        const float* __restrict__ dWru0, const float* __restrict__ dWru1,
        const float* __restrict__ dWc0,  const float* __restrict__ dWc1,
        __bf16* __restrict__ wp) {
    int idx = blockIdx.x * 256 + threadIdx.x;
    if (idx >= 49152) return;
    int half = idx / 24576;
    int li = idx - half * 24576;
    const float* Wru0 = half ? dWru0 : eWru0;
    const float* Wru1 = half ? dWru1 : eWru1;
    const float* Wc0  = half ? dWc0  : eWc0;
    const float* Wc1  = half ? dWc1  : eWc1;
    float v;
    if (li < 16384) {
        const float* W = (li < 8192) ? Wru0 : Wru1;
        int l2 = li & 8191;
        int d = l2 >> 6, f = l2 & 63;
        v = W[(1 + f) * 128 + d];
    } else {
        int l2 = li - 16384;
        const float* W = (l2 < 4096) ? Wc0 : Wc1;
        int l3 = l2 & 4095;
        int d = l3 >> 6, f = l3 & 63;
        v = W[(1 + f) * 64 + d];
    }
    wp[idx] = (__bf16)v;
}

__global__ __launch_bounds__(256) void prep_xe(const float* __restrict__ inputs,
        __bf16* __restrict__ XeT) {
    int idx = blockIdx.x * 256 + threadIdx.x;
    int c = idx >> 10, j = idx & 1023;
    int s = c >> 4, b = c & 15;
    float v = (j < NN) ? inputs[(b * SS + s) * NN + j] : 0.f;
    XeT[c * 1024 + j] = (__bf16)v;
}

// ---------------- bf16 MFMA GEMM (aggXe) ----------------
__global__ __launch_bounds__(256) void gemm_bf(const __bf16* __restrict__ A,
        const __bf16* __restrict__ BT, float* __restrict__ C, int cstride) {
    __shared__ __align__(16) __bf16 As[2][2048];
    __shared__ __align__(16) __bf16 Bs[2][2048];
    int t = threadIdx.x;
    int bm = blockIdx.x * 64;
    int tile = blockIdx.y;
    const __bf16* Bbase = BT + tile * 65536;
    int am = t >> 2;
    int ag = ((t & 3) - (am >> 1)) & 3;
    const __bf16* agp = A + (bm + am) * 1024 + ag * 8;
    const __bf16* bgp = Bbase + am * 1024 + ag * 8;
    int w = t >> 6, l = t & 63, lr = l & 15, lh = l >> 4;
    int ldso = t * 8;
    f32x4 acc[4];
#pragma unroll
    for (int i = 0; i < 4; i++) acc[i] = (f32x4){0.f, 0.f, 0.f, 0.f};

    glds16(agp, &As[0][ldso]);
    glds16(bgp, &Bs[0][ldso]);
    __syncthreads();
    int cur = 0;
    for (int it = 0; it < 32; ++it) {
        if (it < 31) {
            glds16(agp + (it + 1) * 32, &As[cur ^ 1][ldso]);
            glds16(bgp + (it + 1) * 32, &Bs[cur ^ 1][ldso]);
        }
        int arow = w * 16 + lr;
        int asw = (lh + (arow >> 1)) & 3;
        bf16x8 af = *(const bf16x8*)&As[cur][arow * 32 + asw * 8];
#pragma unroll
        for (int ct = 0; ct < 4; ++ct) {
            int nrow = ct * 16 + lr;
            int bsw = (lh + (nrow >> 1)) & 3;
            bf16x8 bv = *(const bf16x8*)&Bs[cur][nrow * 32 + bsw * 8];
            acc[ct] = __builtin_amdgcn_mfma_f32_16x16x32_bf16(af, bv, acc[ct], 0, 0, 0);
        }
        __syncthreads();
        cur ^= 1;
    }
#pragma unroll
    for (int ct = 0; ct < 4; ++ct)
#pragma unroll
        for (int r = 0; r < 4; ++r) {
            int m_loc = w * 16 + lh * 4 + r;
            C[(bm + m_loc) * cstride + tile * 64 + ct * 16 + lr] = acc[ct][r];
        }
}

// ---------------- persistent recurrence (h,u in LDS; depth-6 B pipe) --------
struct RA {
    const __bf16 *A;
    const __bf16 *W0Te, *W1Te, *Wc0Te, *Wc1Te;
    const __bf16 *W0Td, *W1Td, *Wc0Td, *Wc1Td;
    __bf16 *HbT, *RHbT;
    const float *inputs, *aggXe, *rowsum;
    const float *eWru0, *eWru1, *ebru, *eWc0, *eWc1, *ebc;
    const float *dWru0, *dWru1, *dbru, *dWc0, *dWc1, *dbc;
    const float *projw, *projb;
    float *outputs;
    unsigned int *ctr;
};

__global__ __launch_bounds__(512, 2) void recur(RA a) {
    __shared__ __align__(16) __bf16 Bs[2][4096];
    __shared__ __align__(16) __bf16 Ag[4096];
    __shared__ __align__(16) __bf16 RHs[4096];
    __shared__ __align__(16) float hs[64][68];   // block-private h (fp32)
    __shared__ __align__(16) float us[64][68];   // block-private u gate
    __shared__ float xs[64], axs[64], w0x[128], w1x[128], bbs[128], pws[64];
    __shared__ float pp[2][64];
    int t = threadIdx.x;
    int bid = blockIdx.x;
    int b = bid & 15, jb = bid >> 4;
    int bm = jb * 64;
    unsigned int* ctr = a.ctr + b * 64;        // 256B-padded counters
    if (t < 64) pws[t] = a.projw[t];
    float pb = a.projb[0];
    int r64 = t >> 3, s8 = t & 7;
    int gc = (s8 - r64) & 7;
    int ldso = t * 8;
    int w = t >> 6, l = t & 63, lr = l & 15, lh = l >> 4;
    int wr = w & 3, wc = w >> 2;
    int arow = wr * 16 + lr;
    unsigned int phase = 0;
    // zero h state in LDS
    for (int i = t; i < 64 * 68; i += 512) ((float*)hs)[i] = 0.f;

    // A operand fragments (read-only; compiler may rematerialize from L2)
    bf16x8 Areg[16][2];
    {
        const __bf16* arp = a.A + (size_t)(bm + arow) * 1024 + lh * 8;
#pragma unroll
        for (int it = 0; it < 16; ++it) {
            Areg[it][0] = *(const bf16x8*)(arp + it * 64);
            Areg[it][1] = *(const bf16x8*)(arp + it * 64 + 32);
        }
    }
    __syncthreads();

    for (int step = 0; step < SS + HH; ++step) {
        bool dec = step >= SS;
        // ===================== PHASE 1 (r,u gate) =====================
        {
            const __bf16* W0T = dec ? a.W0Td : a.W0Te;
            const __bf16* W1T = dec ? a.W1Td : a.W1Te;
            const float* Wru0 = dec ? a.dWru0 : a.eWru0;
            const float* Wru1 = dec ? a.dWru1 : a.eWru1;
            const float* bru  = dec ? a.dbru  : a.ebru;
            const u64* gpbq = (const u64*)(a.HbT + (size_t)(b * 64 + r64) * 1024 + gc * 8);
            U64x2 P[16];   // staggered: ≤6 live at once
#pragma unroll
            for (int i = 0; i < 6; ++i) P[i] = sysld16(gpbq + i * 16);
            if (t < 64) {
                int j = bm + t;
                if (!dec) {
                    xs[t] = (j < NN) ? a.inputs[(b * SS + step) * NN + j] : 0.f;
                    axs[t] = a.aggXe[j * 192 + step * 16 + b];
                } else if (step == SS) {
                    xs[t] = 0.f; axs[t] = 0.f;     // decoder y0 = 0
                } else {
                    const float* hp = &hs[t][0];
                    float acc = 0.f;
#pragma unroll
                    for (int d2 = 0; d2 < 64; d2 += 4) {
                        float4 v = *(const float4*)(hp + d2);
                        acc += v.x * pws[d2] + v.y * pws[d2 + 1]
                             + v.z * pws[d2 + 2] + v.w * pws[d2 + 3];
                    }
                    xs[t] = acc + pb;              // y_prev = proj(h)
                }
            } else if (t < 192) {
                int d = t - 64;
                w0x[d] = Wru0[d]; w1x[d] = Wru1[d]; bbs[d] = bru[d];
            }
            f32x4 acc0 = (f32x4){0.f, 0.f, 0.f, 0.f};
            f32x4 acc1 = (f32x4){0.f, 0.f, 0.f, 0.f};
            ((u64*)&Bs[0][ldso])[0] = P[0].x;
            ((u64*)&Bs[0][ldso])[1] = P[0].y;
            __syncthreads();
#pragma unroll
            for (int it = 0; it < 16; ++it) {
                int cur = it & 1;
                if (it + 6 < 16) P[it + 6] = sysld16(gpbq + (it + 6) * 16);
#pragma unroll
                for (int kk = 0; kk < 2; ++kk) {
                    int ca = kk * 4 + lh;
                    bf16x8 af = Areg[it][kk];
                    int n0 = wc * 32 + lr;
                    bf16x8 bv0 = *(const bf16x8*)&Bs[cur][n0 * 64 + (((ca + n0) & 7) << 3)];
                    acc0 = __builtin_amdgcn_mfma_f32_16x16x32_bf16(af, bv0, acc0, 0, 0, 0);
                    int n1 = n0 + 16;
                    bf16x8 bv1 = *(const bf16x8*)&Bs[cur][n1 * 64 + (((ca + n1) & 7) << 3)];
                    acc1 = __builtin_amdgcn_mfma_f32_16x16x32_bf16(af, bv1, acc1, 0, 0, 0);
                }
                if (it < 15) {
                    ((u64*)&Bs[cur ^ 1][ldso])[0] = P[it + 1].x;
                    ((u64*)&Bs[cur ^ 1][ldso])[1] = P[it + 1].y;
                }
                __syncthreads();
            }
            {
                f32x4 acc[2] = {acc0, acc1};
#pragma unroll
                for (int ct = 0; ct < 2; ++ct)
#pragma unroll
                    for (int r = 0; r < 4; ++r) {
                        int m = wr * 16 + lh * 4 + r;
                        int d = wc * 32 + ct * 16 + lr;
                        Ag[m * 64 + ((((d >> 3) + m) & 7) << 3) + (d & 7)] = (__bf16)acc[ct][r];
                    }
            }
            __syncthreads();
            // decoder: axs = (A@H)·pw + pb·rowsum == A @ y_prev
            if (dec && step > SS && t < 64) {
                float accx = 0.f;
#pragma unroll
                for (int seg = 0; seg < 8; ++seg) {
                    const __bf16* ap = &Ag[t * 64 + (((seg + t) & 7) << 3)];
#pragma unroll
                    for (int q = 0; q < 8; q++) accx += (float)ap[q] * pws[seg * 8 + q];
                }
                axs[t] = accx + pb * a.rowsum[bm + t];
            }
            // ---- gate GEMM: K=64(h)+64(agg), N=128; W frags direct global --
            f32x4 g[4];
#pragma unroll
            for (int i = 0; i < 4; i++) g[i] = (f32x4){0.f, 0.f, 0.f, 0.f};
#pragma unroll
            for (int h2 = 0; h2 < 2; ++h2) {
                bf16x8 ah = pack8(&hs[arow][h2 * 32 + lh * 8]);
                int sega = h2 * 4 + lh;
                bf16x8 agf = *(const bf16x8*)&Ag[arow * 64 + (((sega + arow) & 7) << 3)];
#pragma unroll
                for (int ct = 0; ct < 4; ++ct) {
                    int n = wc * 64 + ct * 16 + lr;
                    bf16x8 w0f = *(const bf16x8*)&W0T[n * 64 + sega * 8];
                    bf16x8 w1f = *(const bf16x8*)&W1T[n * 64 + sega * 8];
                    g[ct] = __builtin_amdgcn_mfma_f32_16x16x32_bf16(ah, w0f, g[ct], 0, 0, 0);
                    g[ct] = __builtin_amdgcn_mfma_f32_16x16x32_bf16(agf, w1f, g[ct], 0, 0, 0);
                }
            }
            __syncthreads();   // axs ready
#pragma unroll
            for (int ct = 0; ct < 4; ++ct) {
                int d = wc * 64 + ct * 16 + lr;
                float rh4[4];
#pragma unroll
                for (int r = 0; r < 4; ++r) {
                    int m = wr * 16 + lh * 4 + r;
                    float pre = g[ct][r] + xs[m] * w0x[d] + axs[m] * w1x[d] + bbs[d];
                    float sg = 1.f / (1.f + expf(-pre));
                    if (d < 64) {
                        float rh = sg * hs[m][d];
                        RHs[m * 64 + ((((d >> 3) + m) & 7) << 3) + (d & 7)] = (__bf16)rh;
                        rh4[r] = rh;
                    } else {
                        us[m][d - 64] = sg;        // block-private (LDS)
                    }
                }
                if (d < 64)
                    sysst8(&a.RHbT[((size_t)(b * 64 + d)) * 1024 + bm + wr * 16 + lh * 4],
                           pack4bf(rh4[0], rh4[1], rh4[2], rh4[3]));
            }
        }
        bbar(ctr, 16u * (++phase));
        // ===================== PHASE 2 (candidate + update) =====================
        {
            const __bf16* WcT0 = dec ? a.Wc0Td : a.Wc0Te;
            const __bf16* WcT1 = dec ? a.Wc1Td : a.Wc1Te;
            const float* Wc0 = dec ? a.dWc0 : a.eWc0;
            const float* Wc1 = dec ? a.dWc1 : a.eWc1;
            const float* bc  = dec ? a.dbc  : a.ebc;
            const u64* gpbq = (const u64*)(a.RHbT + (size_t)(b * 64 + r64) * 1024 + gc * 8);
            U64x2 P[16];
#pragma unroll
            for (int i = 0; i < 6; ++i) P[i] = sysld16(gpbq + i * 16);
            if (t >= 64 && t < 128) {
                int d = t - 64;
                w0x[d] = Wc0[d]; w1x[d] = Wc1[d]; bbs[d] = bc[d];
            }
            f32x4 acc0 = (f32x4){0.f, 0.f, 0.f, 0.f};
            f32x4 acc1 = (f32x4){0.f, 0.f, 0.f, 0.f};
            ((u64*)&Bs[0][ldso])[0] = P[0].x;
            ((u64*)&Bs[0][ldso])[1] = P[0].y;
            __syncthreads();
#pragma unroll
            for (int it = 0; it < 16; ++it) {
                int cur = it & 1;
                if (it + 6 < 16) P[it + 6] = sysld16(gpbq + (it + 6) * 16);
#pragma unroll
                for (int kk = 0; kk < 2; ++kk) {
                    int ca = kk * 4 + lh;
                    bf16x8 af = Areg[it][kk];
                    int n0 = wc * 32 + lr;
                    bf16x8 bv0 = *(const bf16x8*)&Bs[cur][n0 * 64 + (((ca + n0) & 7) << 3)];
                    acc0 = __builtin_amdgcn_mfma_f32_16x16x32_bf16(af, bv0, acc0, 0, 0, 0);
                    int n1 = n0 + 16;
                    bf16x8 bv1 = *(const bf16x8*)&Bs[cur][n1 * 64 + (((ca + n1) & 7) << 3)];
                    acc1 = __builtin_amdgcn_mfma_f32_16x16x32_bf16(af, bv1, acc1, 0, 0, 0);
                }
                if (it < 15) {
                    ((u64*)&Bs[cur ^ 1][ldso])[0] = P[it + 1].x;
                    ((u64*)&Bs[cur ^ 1][ldso])[1] = P[it + 1].y;
                }
                __syncthreads();
            }
            {
                f32x4 acc[2] = {acc0, acc1};
#pragma unroll
                for (int ct = 0; ct < 2; ++ct)
#pragma unroll
                    for (int r = 0; r < 4; ++r) {
                        int m = wr * 16 + lh * 4 + r;
                        int d = wc * 32 + ct * 16 + lr;
                        Ag[m * 64 + ((((d >> 3) + m) & 7) << 3) + (d & 7)] = (__bf16)acc[ct][r];
                    }
            }
            __syncthreads();
            // ---- gate GEMM: N=64; A-operands from LDS (RHs, Ag) ----
            f32x4 g[2];
            g[0] = (f32x4){0.f, 0.f, 0.f, 0.f};
            g[1] = (f32x4){0.f, 0.f, 0.f, 0.f};
#pragma unroll
            for (int h2 = 0; h2 < 2; ++h2) {
                int sega = h2 * 4 + lh;
                int aslot = arow * 64 + (((sega + arow) & 7) << 3);
                bf16x8 ah = *(const bf16x8*)&RHs[aslot];
                bf16x8 agf = *(const bf16x8*)&Ag[aslot];
#pragma unroll
                for (int ct = 0; ct < 2; ++ct) {
                    int n = wc * 32 + ct * 16 + lr;
                    bf16x8 w0f = *(const bf16x8*)&WcT0[n * 64 + sega * 8];
                    bf16x8 w1f = *(const bf16x8*)&WcT1[n * 64 + sega * 8];
                    g[ct] = __builtin_amdgcn_mfma_f32_16x16x32_bf16(ah, w0f, g[ct], 0, 0, 0);
                    g[ct] = __builtin_amdgcn_mfma_f32_16x16x32_bf16(agf, w1f, g[ct], 0, 0, 0);
                }
            }
            float part[4] = {0.f, 0.f, 0.f, 0.f};
#pragma unroll
            for (int ct = 0; ct < 2; ++ct) {
                int d = wc * 32 + ct * 16 + lr;
                float hn4[4];
#pragma unroll
                for (int r = 0; r < 4; ++r) {
                    int m = wr * 16 + lh * 4 + r;
                    float pre = g[ct][r] + xs[m] * w0x[d] + axs[m] * w1x[d] + bbs[d];
                    float cv = tanhf(pre);
                    float u = us[m][d];
                    float hold = hs[m][d];
                    float hn = u * hold + (1.f - u) * cv;
                    hs[m][d] = hn;                 // block-private (LDS)
                    hn4[r] = hn;
                    if (dec) part[r] += hn * pws[d];
                }
                sysst8(&a.HbT[((size_t)(b * 64 + d)) * 1024 + bm + wr * 16 + lh * 4],
                       pack4bf(hn4[0], hn4[1], hn4[2], hn4[3]));
            }
            if (dec) {
#pragma unroll
                for (int r = 0; r < 4; ++r) {
#pragma unroll
                    for (int off = 1; off < 16; off <<= 1)
                        part[r] += __shfl_xor(part[r], off);
                }
                if (lr == 0) {
#pragma unroll
                    for (int r = 0; r < 4; ++r) pp[wc][wr * 16 + lh * 4 + r] = part[r];
                }
                __syncthreads();
                if (t < 64) {
                    float y = pp[0][t] + pp[1][t] + pb;
                    int j = bm + t;
                    if (j < NN) a.outputs[(b * HH + (step - SS)) * NN + j] = y;
                }
            }
        }
        bbar(ctr, 16u * (++phase));
    }
}

// ---------------- loss ----------------
__global__ __launch_bounds__(256) void loss1(const float* __restrict__ outs,
        const float* __restrict__ tgt, float* __restrict__ part) {
    __shared__ float red[256];
    int t = blockIdx.x * 256 + threadIdx.x;
    float s = 0.f;
    for (int i = t; i < BB * HH * NN; i += 256 * 256) {
        float dd = outs[i] - tgt[i];
        s += dd * dd;
    }
    red[threadIdx.x] = s;
    __syncthreads();
    for (int w = 128; w > 0; w >>= 1) {
        if (threadIdx.x < w) red[threadIdx.x] += red[threadIdx.x + w];
        __syncthreads();
    }
    if (threadIdx.x == 0) part[blockIdx.x] = red[0];
}

__global__ __launch_bounds__(256) void loss2(const float* __restrict__ part,
        float* __restrict__ loss) {
    __shared__ double red[256];
    int t = threadIdx.x;
    red[t] = (double)part[t];
    __syncthreads();
    for (int w = 128; w > 0; w >>= 1) {
        if (t < w) red[t] += red[t + w];
        __syncthreads();
    }
    if (t == 0) loss[0] = (float)(red[0] / (double)(BB * HH * NN));
}

// ---------------- host ----------------
extern "C" void kernel_launch(void* const* d_in, const int* in_sizes, int n_in,
                              void* d_out, int out_size, void* d_ws, size_t ws_size,
                              hipStream_t stream) {
    const float* inputs  = (const float*)d_in[0];
    const float* ein     = (const float*)d_in[1];
    const float* targets = (const float*)d_in[2];
    const float* u_noise = (const float*)d_in[3];
    const float* c1w = (const float*)d_in[4];
    const float* c1b = (const float*)d_in[5];
    const float* c2w = (const float*)d_in[6];
    const float* c2b = (const float*)d_in[7];
    const float* fcw = (const float*)d_in[8];
    const float* fcb = (const float*)d_in[9];
    const float* Wa  = (const float*)d_in[10];
    const float* Wb  = (const float*)d_in[11];
    const float* b1  = (const float*)d_in[12];
    const float* W2  = (const float*)d_in[13];
    const float* b2  = (const float*)d_in[14];
    const float* eWru0 = (const float*)d_in[15];
    const float* eWru1 = (const float*)d_in[16];
    const float* ebru  = (const float*)d_in[17];
    const float* eWc0  = (const float*)d_in[18];
    const float* eWc1  = (const float*)d_in[19];
    const float* ebc   = (const float*)d_in[20];
    const float* dWru0 = (const float*)d_in[21];
    const float* dWru1 = (const float*)d_in[22];
    const float* dbru  = (const float*)d_in[23];
    const float* dWc0  = (const float*)d_in[24];
    const float* dWc1  = (const float*)d_in[25];
    const float* dbc   = (const float*)d_in[26];
    const float* projw = (const float*)d_in[27];
    const float* projb = (const float*)d_in[28];

    float* out = (float*)d_out;
    float* mask    = out;
    float* outputs = out + NN * NN;
    float* loss    = out + NN * NN + BB * HH * NN;

    float* ws = (float*)d_ws;
    float*  f_part = ws;                          // 64,000
    float*  fbuf   = ws + 64000;                  // 128,000
    float*  fa     = ws + 192000;                 // 128,000
    float*  fb     = ws + 320000;                 // 128,000
    float*  deg    = ws + 448000;                 // 1,024
    float*  lossp  = ws + 449024;                 // 256
    float*  rowsum = ws + 449280;                 // 1,024
    float*  w2r    = ws + 450304;                 // 1,280
    __bf16* wp     = (__bf16*)(ws + 451584);      // 49,152 bf16
    __bf16* A_bf   = (__bf16*)(ws + 476160);      // 1,048,576 bf16
    __bf16* XeT    = (__bf16*)(ws + 1000448);     // 196,608 bf16
    float*  aggXe  = ws + 1098752;                // 196,608 f32
    __bf16* RHbT   = (__bf16*)(ws + 1295360);     // 1,048,576 bf16
    __bf16* HbT    = (__bf16*)(ws + 1819648);     // 1,048,576 bf16 <- zero region
    unsigned int* ctr = (unsigned int*)(ws + 2343936);  // 1024 u32 <- zero region
    const int ZLEN = 524288 + 1024;

    __bf16 *eW0T = wp, *eW1T = wp + 8192, *eWc0T = wp + 16384, *eWc1T = wp + 20480;
    __bf16 *dW0T = wp + 24576, *dW1T = wp + 32768, *dWc0T = wp + 40960, *dWc1T = wp + 45056;

    init_zero<<<2048, 256, 0, stream>>>((float*)HbT, ZLEN);
    prep_w<<<192, 256, 0, stream>>>(eWru0, eWru1, eWc0, eWc1, dWru0, dWru1, dWc0, dWc1, wp);
    prep_w2<<<5, 256, 0, stream>>>(c2w, w2r);
    prep_xe<<<768, 256, 0, stream>>>(inputs, XeT);

    // graph head
    s1_conv4<<<dim3(NN, 4), 512, 0, stream>>>(ein, c1w, c1b, w2r, c2b, f_part);
    fc_relu<<<NN, 128, 0, stream>>>(f_part, fcw, fcb, fbuf);
    fafb_k<<<NN, 128, 0, stream>>>(fbuf, Wa, Wb, fa, fb);
    edge_mask<<<dim3(63, 63), 256, 0, stream>>>(fa, fb, b1, W2, b2, u_noise, mask);
    row_deg<<<NN, 256, 0, stream>>>(mask, deg);
    make_A<<<4096, 256, 0, stream>>>(mask, deg, A_bf);
    row_sumA<<<1024, 64, 0, stream>>>(A_bf, rowsum);

    // x-aggregation for all encoder steps
    gemm_bf<<<dim3(16, 3), 256, 0, stream>>>(A_bf, XeT, aggXe, 192);

    // persistent recurrence (cooperative: co-residency for per-batch barriers)
    RA ra;
    ra.A = A_bf;
    ra.W0Te = eW0T; ra.W1Te = eW1T; ra.Wc0Te = eWc0T; ra.Wc1Te = eWc1T;
    ra.W0Td = dW0T; ra.W1Td = dW1T; ra.Wc0Td = dWc0T; ra.Wc1Td = dWc1T;
    ra.HbT = HbT; ra.RHbT = RHbT;
    ra.inputs = inputs; ra.aggXe = aggXe; ra.rowsum = rowsum;
    ra.eWru0 = eWru0; ra.eWru1 = eWru1; ra.ebru = ebru;
    ra.eWc0 = eWc0; ra.eWc1 = eWc1; ra.ebc = ebc;
    ra.dWru0 = dWru0; ra.dWru1 = dWru1; ra.dbru = dbru;
    ra.dWc0 = dWc0; ra.dWc1 = dWc1; ra.dbc = dbc;
    ra.projw = projw; ra.projb = projb;
    ra.outputs = outputs;
    ra.ctr = ctr;
    void* args[] = {&ra};
    hipLaunchCooperativeKernel((const void*)recur, dim3(256), dim3(512), args, 0, stream);

    loss1<<<256, 256, 0, stream>>>(outputs, targets, lossp);
    loss2<<<1, 256, 0, stream>>>(lossp, loss);
}